// Round 4
// baseline (886.242 us; speedup 1.0000x reference)
//
#include <hip/hip_runtime.h>

#define N 4096
#define D 512
#define BIG 1e30f
#define ROUNDS 12
#define CMAX 2048
#define NW (N / 32)

typedef unsigned long long u64;
typedef unsigned short u16;
typedef __bf16 bf16x8 __attribute__((ext_vector_type(8)));
typedef float floatx4 __attribute__((ext_vector_type(4)));

// ---------------- row squared norms
__global__ __launch_bounds__(256) void rowsq_kernel(const float* __restrict__ x1,
                                                    const float* __restrict__ x2,
                                                    float* __restrict__ sq) {
    int m = blockIdx.y;
    const float* x = m ? x2 : x1;
    int wave = threadIdx.x >> 6, lane = threadIdx.x & 63;
    int row = blockIdx.x * 4 + wave;
    const float4* xr = (const float4*)(x + (size_t)row * D);
    float4 a = xr[lane * 2], b = xr[lane * 2 + 1];
    float s = 0.f;
    s = fmaf(a.x, a.x, s); s = fmaf(a.y, a.y, s); s = fmaf(a.z, a.z, s); s = fmaf(a.w, a.w, s);
    s = fmaf(b.x, b.x, s); s = fmaf(b.y, b.y, s); s = fmaf(b.z, b.z, s); s = fmaf(b.w, b.w, s);
#pragma unroll
    for (int off = 32; off > 0; off >>= 1) s += __shfl_down(s, off, 64);
    if (lane == 0) sq[(size_t)m * N + row] = s;
}

// ---------------- dist via bf16-split MFMA GEMM (unchanged from R3)
#define BM 128
#define BN 128
#define BK 32

__global__ __launch_bounds__(256) void gemm_dist_kernel(const float* __restrict__ x1,
                                                        const float* __restrict__ x2,
                                                        const float* __restrict__ sqn,
                                                        float* __restrict__ dist1,
                                                        float* __restrict__ dist2,
                                                        int m0) {
    const int m = m0 + blockIdx.z;
    const float* x = m ? x2 : x1;
    const float* SQ = sqn + (size_t)m * N;
    float* dist = m ? dist2 : dist1;

    __shared__ u16 Ah[BM * BK];
    __shared__ u16 Al[BM * BK];
    __shared__ u16 Bh[BN * BK];
    __shared__ u16 Bl[BN * BK];

    const int tid = threadIdx.x;
    const int wave = tid >> 6, lane = tid & 63;
    const int wm = wave >> 1, wn = wave & 1;
    const int row0 = blockIdx.y * BM, col0 = blockIdx.x * BN;

    floatx4 acc[4][4] = {};

    const int sr = tid >> 1;
    const int sh = tid & 1;

    for (int k0 = 0; k0 < D; k0 += BK) {
        __syncthreads();
        {
            const float4* ga = (const float4*)(x + (size_t)(row0 + sr) * D + k0 + sh * 16);
            const float4* gb = (const float4*)(x + (size_t)(col0 + sr) * D + k0 + sh * 16);
            float4 av[4], bv[4];
#pragma unroll
            for (int q = 0; q < 4; ++q) { av[q] = ga[q]; bv[q] = gb[q]; }
            int hA[8], lA[8], hB[8], lB[8];
#pragma unroll
            for (int q = 0; q < 4; ++q) {
                const float* af = &av[q].x;
                const float* bf = &bv[q].x;
#pragma unroll
                for (int e = 0; e < 2; ++e) {
                    unsigned u0 = __float_as_uint(af[2 * e]);
                    unsigned u1 = __float_as_uint(af[2 * e + 1]);
                    hA[q * 2 + e] = (int)((u0 >> 16) | (u1 & 0xffff0000u));
                    float l0 = af[2 * e] - __uint_as_float(u0 & 0xffff0000u);
                    float l1 = af[2 * e + 1] - __uint_as_float(u1 & 0xffff0000u);
                    lA[q * 2 + e] = (int)((__float_as_uint(l0) >> 16) | (__float_as_uint(l1) & 0xffff0000u));
                    unsigned w0 = __float_as_uint(bf[2 * e]);
                    unsigned w1 = __float_as_uint(bf[2 * e + 1]);
                    hB[q * 2 + e] = (int)((w0 >> 16) | (w1 & 0xffff0000u));
                    float m0_ = bf[2 * e] - __uint_as_float(w0 & 0xffff0000u);
                    float m1_ = bf[2 * e + 1] - __uint_as_float(w1 & 0xffff0000u);
                    lB[q * 2 + e] = (int)((__float_as_uint(m0_) >> 16) | (__float_as_uint(m1_) & 0xffff0000u));
                }
            }
            int* dAh = (int*)(Ah + sr * BK + sh * 16);
            int* dAl = (int*)(Al + sr * BK + sh * 16);
            int* dBh = (int*)(Bh + sr * BK + sh * 16);
            int* dBl = (int*)(Bl + sr * BK + sh * 16);
            *(int4*)(dAh) = make_int4(hA[0], hA[1], hA[2], hA[3]);
            *(int4*)(dAh + 4) = make_int4(hA[4], hA[5], hA[6], hA[7]);
            *(int4*)(dAl) = make_int4(lA[0], lA[1], lA[2], lA[3]);
            *(int4*)(dAl + 4) = make_int4(lA[4], lA[5], lA[6], lA[7]);
            *(int4*)(dBh) = make_int4(hB[0], hB[1], hB[2], hB[3]);
            *(int4*)(dBh + 4) = make_int4(hB[4], hB[5], hB[6], hB[7]);
            *(int4*)(dBl) = make_int4(lB[0], lB[1], lB[2], lB[3]);
            *(int4*)(dBl + 4) = make_int4(lB[4], lB[5], lB[6], lB[7]);
        }
        __syncthreads();

        const int fo = (lane >> 4) * 8;
        const int fm = lane & 15;
        bf16x8 ah[4], al[4], bh[4], bl[4];
#pragma unroll
        for (int s = 0; s < 4; ++s) {
            ah[s] = *(bf16x8*)(Ah + (wm * 64 + s * 16 + fm) * BK + fo);
            al[s] = *(bf16x8*)(Al + (wm * 64 + s * 16 + fm) * BK + fo);
            bh[s] = *(bf16x8*)(Bh + (wn * 64 + s * 16 + fm) * BK + fo);
            bl[s] = *(bf16x8*)(Bl + (wn * 64 + s * 16 + fm) * BK + fo);
        }
#pragma unroll
        for (int i = 0; i < 4; ++i)
#pragma unroll
            for (int j = 0; j < 4; ++j) {
                acc[i][j] = __builtin_amdgcn_mfma_f32_16x16x32_bf16(ah[i], bh[j], acc[i][j], 0, 0, 0);
                acc[i][j] = __builtin_amdgcn_mfma_f32_16x16x32_bf16(al[i], bh[j], acc[i][j], 0, 0, 0);
                acc[i][j] = __builtin_amdgcn_mfma_f32_16x16x32_bf16(ah[i], bl[j], acc[i][j], 0, 0, 0);
            }
    }

    const int lr = lane & 15;
    const int lq = lane >> 4;
    float sc[4];
#pragma unroll
    for (int ns = 0; ns < 4; ++ns) sc[ns] = SQ[col0 + wn * 64 + ns * 16 + lr];
#pragma unroll
    for (int ms = 0; ms < 4; ++ms) {
        const int rb = row0 + wm * 64 + ms * 16 + lq * 4;
        float srow[4];
#pragma unroll
        for (int r = 0; r < 4; ++r) srow[r] = SQ[rb + r];
#pragma unroll
        for (int ns = 0; ns < 4; ++ns) {
            const int col = col0 + wn * 64 + ns * 16 + lr;
#pragma unroll
            for (int r = 0; r < 4; ++r) {
                const int row = rb + r;
                float d2 = srow[r] + sc[ns] - 2.0f * acc[ms][ns][r];
                float dv = (row == col) ? BIG : sqrtf(fmaxf(d2, 1e-12f));
                dist[(size_t)row * N + col] = dv;
            }
        }
    }
}

// ---------------- Boruvka common init
__global__ void boruvka_init(int* __restrict__ comp, u64* __restrict__ compBest,
                             int* __restrict__ comp_c,
                             int* __restrict__ cnt, int* __restrict__ numComp,
                             int* __restrict__ numC1, float* __restrict__ accum) {
    int idx = blockIdx.x * blockDim.x + threadIdx.x;
    if (idx < 2 * N) {
        comp[idx] = idx & (N - 1);
        compBest[idx] = ~0ull;
    }
    if (comp_c && idx < 2 * CMAX) comp_c[idx] = idx & (CMAX - 1);
    if (idx == 0) {
        cnt[0] = 0; cnt[1] = 0;
        numComp[0] = N; numComp[1] = N;
        if (numC1) { numC1[0] = 0; numC1[1] = 0; }
        accum[0] = 0.f;
    }
}

// ---------------- full-matrix scan (round 1, and Tier B/C all rounds)
__global__ __launch_bounds__(256) void boruvka_scan(const float* __restrict__ dist1,
                                                    const float* __restrict__ dist2,
                                                    const int* __restrict__ comp,
                                                    u64* __restrict__ compBest,
                                                    const int* __restrict__ numComp,
                                                    int m0) {
    const int m = m0 + blockIdx.y;
    if (numComp[m] <= 1) return;
    const float* dist = (m == 0) ? dist1 : dist2;
    const int* cp = comp + (size_t)m * N;
    u64* cb = compBest + (size_t)m * N;
    const int r = blockIdx.x;
    const int myc = cp[r];
    const float4* row4 = (const float4*)(dist + (size_t)r * N);
    const int4* cp4 = (const int4*)cp;
    const int t = threadIdx.x;
    u64 best = ~0ull;
#pragma unroll
    for (int k = 0; k < 4; ++k) {
        int c4 = t + 256 * k;
        float4 v = row4[c4];
        int4 cj = cp4[c4];
        int j0 = c4 * 4;
        u64 p0 = (cj.x != myc) ? ((((u64)__float_as_uint(v.x)) << 32) | (unsigned)(j0 + 0)) : ~0ull;
        u64 p1 = (cj.y != myc) ? ((((u64)__float_as_uint(v.y)) << 32) | (unsigned)(j0 + 1)) : ~0ull;
        u64 p2 = (cj.z != myc) ? ((((u64)__float_as_uint(v.z)) << 32) | (unsigned)(j0 + 2)) : ~0ull;
        u64 p3 = (cj.w != myc) ? ((((u64)__float_as_uint(v.w)) << 32) | (unsigned)(j0 + 3)) : ~0ull;
        u64 q0 = p0 < p1 ? p0 : p1;
        u64 q1 = p2 < p3 ? p2 : p3;
        u64 q = q0 < q1 ? q0 : q1;
        best = q < best ? q : best;
    }
#pragma unroll
    for (int off = 32; off > 0; off >>= 1) {
        u64 o = __shfl_down(best, off, 64);
        best = o < best ? o : best;
    }
    if ((t & 63) == 0) atomicMin(cb + myc, best);
}

// ---------------- Tier B/C merge (R3, unchanged)
__global__ __launch_bounds__(1024) void boruvka_merge(int* __restrict__ comp,
                                                      u64* __restrict__ compBest,
                                                      float* __restrict__ deaths,
                                                      int* __restrict__ cnt,
                                                      int* __restrict__ numComp,
                                                      int m0) {
    const int m = m0 + blockIdx.x;
    if (numComp[m] <= 1) return;
    int* cp = comp + (size_t)m * N;
    u64* cb = compBest + (size_t)m * N;
    float* dth = deaths + (size_t)m * N;
    const int t = threadIdx.x;
    __shared__ int pa[N];
    __shared__ int pb[N];
    __shared__ int done;
    __shared__ unsigned flagbits[NW];

    for (int c = t; c < N; c += 1024) {
        u64 best = cb[c];
        int p = c;
        if (best != ~0ull) {
            int j = (int)(unsigned)best;
            int c2 = cp[j];
            u64 best2 = cb[c2];
            int j2 = (int)(unsigned)best2;
            bool mutual = (cp[j2] == c);
            if (!(mutual && c < c2)) {
                p = c2;
                int idx = atomicAdd(cnt + m, 1);
                dth[idx] = __uint_as_float((unsigned)(best >> 32));
            }
        }
        pa[c] = p;
    }

    int* A = pa;
    int* B = pb;
    while (true) {
        __syncthreads();
        if (t == 0) done = 1;
        __syncthreads();
        bool ch = false;
        for (int c = t; c < N; c += 1024) {
            int g = A[A[c]];
            B[c] = g;
            ch |= (g != A[c]);
        }
        if (ch) done = 0;
        __syncthreads();
        int* tmp = A; A = B; B = tmp;
        if (done) break;
    }

    for (int w = t; w < NW; w += 1024) flagbits[w] = 0u;
    __syncthreads();
    for (int i = t; i < N; i += 1024) {
        int root = A[cp[i]];
        cp[i] = root;
        atomicOr(&flagbits[root >> 5], 1u << (root & 31));
    }
    for (int c = t; c < N; c += 1024) cb[c] = ~0ull;
    __syncthreads();
    if (t < 64) {
        int s = 0;
        for (int w = t; w < NW; w += 64) s += __popc(flagbits[w]);
#pragma unroll
        for (int off = 32; off > 0; off >>= 1) s += __shfl_down(s, off, 64);
        if (t == 0) numComp[m] = s;
    }
}

// ---------------- Tier A: merge round 1 + dense relabel + member lists
__global__ __launch_bounds__(1024) void merge1_kernel(int* __restrict__ comp,
                                                      u64* __restrict__ compBest,
                                                      float* __restrict__ deaths,
                                                      int* __restrict__ cnt,
                                                      int* __restrict__ numComp,
                                                      int* __restrict__ numC1,
                                                      int* __restrict__ memberList,
                                                      int* __restrict__ compStart) {
    const int m = blockIdx.x;
    int* cp = comp + (size_t)m * N;
    u64* cb = compBest + (size_t)m * N;
    float* dth = deaths + (size_t)m * N;
    int* mlist = memberList + (size_t)m * N;
    int* cstart = compStart + (size_t)m * (CMAX + 1);
    const int t = threadIdx.x;

    __shared__ int pa[N];
    __shared__ int pb[N];
    __shared__ unsigned flagbits[NW];
    __shared__ int wpc[NW];
    __shared__ int cnts[CMAX];
    __shared__ int cnts2[CMAX];
    __shared__ int done;

    // hook (round 1: cp[i] == i)
    for (int c = t; c < N; c += 1024) {
        u64 best = cb[c];
        int p = c;
        if (best != ~0ull) {
            int j = (int)(unsigned)best;
            int c2 = cp[j];
            u64 best2 = cb[c2];
            int j2 = (int)(unsigned)best2;
            bool mutual = (cp[j2] == c);
            if (!(mutual && c < c2)) {
                p = c2;
                int idx = atomicAdd(cnt + m, 1);
                dth[idx] = __uint_as_float((unsigned)(best >> 32));
            }
        }
        pa[c] = p;
    }

    int* A = pa;
    int* B = pb;
    while (true) {
        __syncthreads();
        if (t == 0) done = 1;
        __syncthreads();
        bool ch = false;
        for (int c = t; c < N; c += 1024) {
            int g = A[A[c]];
            B[c] = g;
            ch |= (g != A[c]);
        }
        if (ch) done = 0;
        __syncthreads();
        int* tmp = A; A = B; B = tmp;
        if (done) break;
    }

    // flags of roots
    for (int w = t; w < NW; w += 1024) flagbits[w] = 0u;
    __syncthreads();
    for (int i = t; i < N; i += 1024)
        atomicOr(&flagbits[A[i] >> 5], 1u << (A[i] & 31));
    __syncthreads();
    // inclusive scan of per-word popcounts (128 words)
    if (t < NW) wpc[t] = __popc(flagbits[t]);
    __syncthreads();
    for (int off = 1; off < NW; off <<= 1) {
        int v = 0;
        if (t < NW) v = wpc[t] + ((t >= off) ? wpc[t - off] : 0);
        __syncthreads();
        if (t < NW) wpc[t] = v;
        __syncthreads();
    }
    // dense relabel comp[i] = denseId(root(i))
    for (int i = t; i < N; i += 1024) {
        int root = A[i];
        int w = root >> 5, b = root & 31;
        int base = w ? wpc[w - 1] : 0;
        unsigned mask = b ? ((1u << b) - 1u) : 0u;
        cp[i] = base + __popc(flagbits[w] & mask);
    }
    // histogram over dense comps
    for (int c = t; c < CMAX; c += 1024) cnts[c] = 0;
    __syncthreads();
    for (int i = t; i < N; i += 1024) atomicAdd(&cnts[cp[i]], 1);
    __syncthreads();
    // inclusive scan over 2048 bins (double-buffered Hillis-Steele)
    int* S = cnts; int* T_ = cnts2;
    for (int off = 1; off < CMAX; off <<= 1) {
        for (int c = t; c < CMAX; c += 1024)
            T_[c] = S[c] + ((c >= off) ? S[c - off] : 0);
        __syncthreads();
        int* tmp = S; S = T_; T_ = tmp;
    }
    // compStart (exclusive) + scatter offsets
    for (int c = t; c <= CMAX; c += 1024) cstart[c] = (c == 0) ? 0 : S[c - 1];
    for (int c = t; c < CMAX; c += 1024) T_[c] = (c == 0) ? 0 : S[c - 1];
    __syncthreads();
    for (int i = t; i < N; i += 1024) {
        int pos = atomicAdd(&T_[cp[i]], 1);
        mlist[pos] = i;
    }
    for (int c = t; c < N; c += 1024) cb[c] = ~0ull;
    if (t == 0) {
        int C1 = wpc[NW - 1];
        numC1[m] = C1;
        numComp[m] = C1;
    }
}

// ---------------- Tier A: contract dist -> distc[C1][C1] (stride CMAX), no global atomics
__global__ __launch_bounds__(256) void contract_kernel(const float* __restrict__ dist1,
                                                       const float* __restrict__ dist2,
                                                       const int* __restrict__ comp,
                                                       const int* __restrict__ memberList,
                                                       const int* __restrict__ compStart,
                                                       const int* __restrict__ numC1,
                                                       float* __restrict__ distc) {
    const int m = blockIdx.y;
    const int c = blockIdx.x;
    const int C1 = numC1[m];
    if (c >= C1) return;
    const float* dist = m ? dist2 : dist1;
    const int* cp = comp + (size_t)m * N;
    const int* mlist = memberList + (size_t)m * N;
    const int* cstart = compStart + (size_t)m * (CMAX + 1);
    float* dcr = distc + ((size_t)m * CMAX + c) * CMAX;
    __shared__ unsigned bins[CMAX];
    const int t = threadIdx.x;
    for (int b = t; b < CMAX; b += 256) bins[b] = 0x7f800000u; // +inf
    __syncthreads();
    const int s0 = cstart[c], s1 = cstart[c + 1];
    for (int k = s0; k < s1; ++k) {
        const int i = mlist[k];
        const float4* row4 = (const float4*)(dist + (size_t)i * N);
        const int4* cp4 = (const int4*)cp;
        for (int q = t; q < N / 4; q += 256) {
            float4 v = row4[q];
            int4 cj = cp4[q];
            atomicMin(&bins[cj.x], __float_as_uint(v.x));
            atomicMin(&bins[cj.y], __float_as_uint(v.y));
            atomicMin(&bins[cj.z], __float_as_uint(v.z));
            atomicMin(&bins[cj.w], __float_as_uint(v.w));
        }
    }
    __syncthreads();
    for (int b = t; b < C1; b += 256)
        dcr[b] = (b == c) ? BIG : __uint_as_float(bins[b]);
}

// ---------------- Tier A: scan on contracted matrix
__global__ __launch_bounds__(256) void scan_c_kernel(const float* __restrict__ distc,
                                                     const int* __restrict__ comp_c,
                                                     u64* __restrict__ compBest,
                                                     const int* __restrict__ numComp,
                                                     const int* __restrict__ numC1) {
    const int m = blockIdx.y;
    if (numComp[m] <= 1) return;
    const int C1 = numC1[m];
    const int r = blockIdx.x;
    if (r >= C1) return;
    const int* cc = comp_c + (size_t)m * CMAX;
    u64* cb = compBest + (size_t)m * N;
    const int myc = cc[r];
    const float4* row4 = (const float4*)(distc + ((size_t)m * CMAX + r) * CMAX);
    const int4* cc4 = (const int4*)cc;
    const int t = threadIdx.x;
    u64 best = ~0ull;
#pragma unroll
    for (int k = 0; k < 2; ++k) {
        int q = t + 256 * k;
        float4 v = row4[q];
        int4 cj = cc4[q];
        int j0 = q * 4;
        u64 p0 = (j0 + 0 < C1 && cj.x != myc) ? ((((u64)__float_as_uint(v.x)) << 32) | (unsigned)(j0 + 0)) : ~0ull;
        u64 p1 = (j0 + 1 < C1 && cj.y != myc) ? ((((u64)__float_as_uint(v.y)) << 32) | (unsigned)(j0 + 1)) : ~0ull;
        u64 p2 = (j0 + 2 < C1 && cj.z != myc) ? ((((u64)__float_as_uint(v.z)) << 32) | (unsigned)(j0 + 2)) : ~0ull;
        u64 p3 = (j0 + 3 < C1 && cj.w != myc) ? ((((u64)__float_as_uint(v.w)) << 32) | (unsigned)(j0 + 3)) : ~0ull;
        u64 q0 = p0 < p1 ? p0 : p1;
        u64 q1 = p2 < p3 ? p2 : p3;
        u64 qq = q0 < q1 ? q0 : q1;
        best = qq < best ? qq : best;
    }
#pragma unroll
    for (int off = 32; off > 0; off >>= 1) {
        u64 o = __shfl_down(best, off, 64);
        best = o < best ? o : best;
    }
    if ((t & 63) == 0) atomicMin(cb + myc, best);
}

// ---------------- Tier A: merge on contracted graph
__global__ __launch_bounds__(1024) void merge_c_kernel(int* __restrict__ comp_c,
                                                       u64* __restrict__ compBest,
                                                       float* __restrict__ deaths,
                                                       int* __restrict__ cnt,
                                                       int* __restrict__ numComp,
                                                       const int* __restrict__ numC1) {
    const int m = blockIdx.x;
    if (numComp[m] <= 1) return;
    const int C1 = numC1[m];
    int* cc = comp_c + (size_t)m * CMAX;
    u64* cb = compBest + (size_t)m * N;
    float* dth = deaths + (size_t)m * N;
    const int t = threadIdx.x;
    __shared__ int pa[CMAX];
    __shared__ int pb[CMAX];
    __shared__ unsigned flagbits[CMAX / 32];
    __shared__ int done;

    for (int c = t; c < C1; c += 1024) {
        u64 best = cb[c];
        int p = c;
        if (best != ~0ull) {
            int j = (int)(unsigned)best;
            int c2 = cc[j];
            u64 best2 = cb[c2];
            int j2 = (int)(unsigned)best2;
            bool mutual = (cc[j2] == c);
            if (!(mutual && c < c2)) {
                p = c2;
                int idx = atomicAdd(cnt + m, 1);
                dth[idx] = __uint_as_float((unsigned)(best >> 32));
            }
        }
        pa[c] = p;
    }

    int* A = pa;
    int* B = pb;
    while (true) {
        __syncthreads();
        if (t == 0) done = 1;
        __syncthreads();
        bool ch = false;
        for (int c = t; c < C1; c += 1024) {
            int g = A[A[c]];
            B[c] = g;
            ch |= (g != A[c]);
        }
        if (ch) done = 0;
        __syncthreads();
        int* tmp = A; A = B; B = tmp;
        if (done) break;
    }

    for (int w = t; w < CMAX / 32; w += 1024) flagbits[w] = 0u;
    __syncthreads();
    for (int j = t; j < C1; j += 1024) {
        int root = A[cc[j]];
        cc[j] = root;
        atomicOr(&flagbits[root >> 5], 1u << (root & 31));
    }
    for (int c = t; c < C1; c += 1024) cb[c] = ~0ull;
    __syncthreads();
    if (t < 64) {
        int s = 0;
        for (int w = t; w < CMAX / 32; w += 64) s += __popc(flagbits[w]);
#pragma unroll
        for (int off = 32; off > 0; off >>= 1) s += __shfl_down(s, off, 64);
        if (t == 0) numComp[m] = s;
    }
}

// ---------------- bitonic sort of 4096 (4095 deaths + one BIG pad) in LDS
__global__ __launch_bounds__(1024) void sort_kernel(float* __restrict__ deaths1,
                                                    float* __restrict__ deaths2) {
    float* deaths = (blockIdx.x == 0) ? deaths1 : deaths2;
    __shared__ float s[N];
    const int tid = threadIdx.x;
    for (int i = tid; i < N; i += 1024)
        s[i] = (i < N - 1) ? deaths[i] : BIG;
    __syncthreads();
    for (int k = 2; k <= N; k <<= 1) {
        for (int jj = k >> 1; jj > 0; jj >>= 1) {
            for (int t = tid; t < N; t += 1024) {
                int ixj = t ^ jj;
                if (ixj > t) {
                    float a = s[t], b = s[ixj];
                    bool up = ((t & k) == 0);
                    bool sw = up ? (a > b) : (a < b);
                    if (sw) { s[t] = b; s[ixj] = a; }
                }
            }
            __syncthreads();
        }
    }
    for (int i = tid; i < N; i += 1024) deaths[i] = s[i];
}

// ---------------- representation loss
__global__ void repr_kernel(const float4* __restrict__ a, const float4* __restrict__ b,
                            float* __restrict__ accum) {
    int idx = blockIdx.x * blockDim.x + threadIdx.x;
    int stride = gridDim.x * blockDim.x;
    float s = 0.f;
    for (int i = idx; i < (N * D / 4); i += stride) {
        float4 va = a[i], vb = b[i];
        float dx = va.x - vb.x, dy = va.y - vb.y, dz = va.z - vb.z, dw = va.w - vb.w;
        s = fmaf(dx, dx, s); s = fmaf(dy, dy, s); s = fmaf(dz, dz, s); s = fmaf(dw, dw, s);
    }
#pragma unroll
    for (int off = 32; off > 0; off >>= 1) s += __shfl_down(s, off, 64);
    if ((threadIdx.x & 63) == 0) atomicAdd(accum, s);
}

// ---------------- final
__global__ __launch_bounds__(1024) void final_kernel(const float* __restrict__ s1,
                                                     const float* __restrict__ s2,
                                                     const float* __restrict__ accum,
                                                     float* __restrict__ out) {
    __shared__ float wsum[16];
    float sum = 0.f;
    for (int i = threadIdx.x; i < N - 1; i += 1024) {
        float a = s1[i], b = s2[i];
        sum += fminf(fabsf(a - b), 0.5f * (a + b));
    }
#pragma unroll
    for (int off = 32; off > 0; off >>= 1) sum += __shfl_down(sum, off, 64);
    int lane = threadIdx.x & 63, wid = threadIdx.x >> 6;
    if (lane == 0) wsum[wid] = sum;
    __syncthreads();
    if (threadIdx.x == 0) {
        float tot = 0.f;
        for (int k = 0; k < 16; ++k) tot += wsum[k];
        out[0] = accum[0] * (1.0f / ((float)N * (float)D)) + tot;
    }
}

extern "C" void kernel_launch(void* const* d_in, const int* in_sizes, int n_in,
                              void* d_out, int out_size, void* d_ws, size_t ws_size,
                              hipStream_t stream) {
    const float* x1 = (const float*)d_in[0];
    const float* x2 = (const float*)d_in[1];
    float* out = (float*)d_out;
    float* ws = (float*)d_ws;

    const size_t nn = (size_t)N * N;
    const size_t cc2 = (size_t)CMAX * CMAX;

    // Tier A layout
    float* dist1 = ws;
    float* dist2 = ws + nn;
    float* distc = ws + 2 * nn;
    u64* compBestA = (u64*)(distc + 2 * cc2);
    int* compA     = (int*)(compBestA + 2 * N);
    int* comp_c    = compA + 2 * N;
    int* memberList = comp_c + 2 * CMAX;
    int* compStart  = memberList + 2 * N;
    float* deathsA  = (float*)(compStart + 2 * (CMAX + 1));
    int* cntA       = (int*)(deathsA + 2 * N);
    int* numCompA   = cntA + 2;
    int* numC1      = numCompA + 2;
    float* accumA   = (float*)(numC1 + 2);
    float* sqA      = accumA + 2;
    const size_t need_A = (size_t)((char*)(sqA + 2 * N) - (char*)ws);

    // Tier B layout (R3)
    const size_t state_floats = 2 * N * 2 + 2 * N + 2 * N + 8 + 2 * N;
    const size_t need_B = (2 * nn + state_floats) * sizeof(float);

    if (ws_size >= need_A) {
        boruvka_init<<<(2 * N + 255) / 256, 256, 0, stream>>>(compA, compBestA, comp_c, cntA, numCompA, numC1, accumA);
        rowsq_kernel<<<dim3(N / 4, 2), 256, 0, stream>>>(x1, x2, sqA);
        repr_kernel<<<512, 256, 0, stream>>>((const float4*)x1, (const float4*)x2, accumA);
        gemm_dist_kernel<<<dim3(N / BN, N / BM, 2), 256, 0, stream>>>(x1, x2, sqA, dist1, dist2, 0);
        // round 1 on full matrix
        boruvka_scan<<<dim3(N, 2), 256, 0, stream>>>(dist1, dist2, compA, compBestA, numCompA, 0);
        merge1_kernel<<<2, 1024, 0, stream>>>(compA, compBestA, deathsA, cntA, numCompA, numC1, memberList, compStart);
        // contract to C1 x C1
        contract_kernel<<<dim3(CMAX, 2), 256, 0, stream>>>(dist1, dist2, compA, memberList, compStart, numC1, distc);
        // remaining rounds on contracted matrix
        for (int r = 1; r < ROUNDS; ++r) {
            scan_c_kernel<<<dim3(CMAX, 2), 256, 0, stream>>>(distc, comp_c, compBestA, numCompA, numC1);
            merge_c_kernel<<<2, 1024, 0, stream>>>(comp_c, compBestA, deathsA, cntA, numCompA, numC1);
        }
        sort_kernel<<<2, 1024, 0, stream>>>(deathsA, deathsA + N);
        final_kernel<<<1, 1024, 0, stream>>>(deathsA, deathsA + N, accumA, out);
    } else if (ws_size >= need_B) {
        u64* compBest = (u64*)(ws + 2 * nn);
        int* comp     = (int*)(compBest + 2 * N);
        float* deaths = (float*)(comp + 2 * N);
        int* cnt      = (int*)(deaths + 2 * N);
        int* numComp  = cnt + 2;
        float* accum  = (float*)(numComp + 2);
        float* sq     = accum + 2;

        boruvka_init<<<(2 * N + 255) / 256, 256, 0, stream>>>(comp, compBest, (int*)0, cnt, numComp, (int*)0, accum);
        rowsq_kernel<<<dim3(N / 4, 2), 256, 0, stream>>>(x1, x2, sq);
        repr_kernel<<<512, 256, 0, stream>>>((const float4*)x1, (const float4*)x2, accum);
        gemm_dist_kernel<<<dim3(N / BN, N / BM, 2), 256, 0, stream>>>(x1, x2, sq, dist1, dist2, 0);
        for (int r = 0; r < ROUNDS; ++r) {
            boruvka_scan<<<dim3(N, 2), 256, 0, stream>>>(dist1, dist2, comp, compBest, numComp, 0);
            boruvka_merge<<<2, 1024, 0, stream>>>(comp, compBest, deaths, cnt, numComp, 0);
        }
        sort_kernel<<<2, 1024, 0, stream>>>(deaths, deaths + N);
        final_kernel<<<1, 1024, 0, stream>>>(deaths, deaths + N, accum, out);
    } else {
        // sequential fallback
        float* dist = ws;
        u64* compBest = (u64*)(ws + nn);
        int* comp     = (int*)(compBest + 2 * N);
        float* deaths = (float*)(comp + 2 * N);
        int* cnt      = (int*)(deaths + 2 * N);
        int* numComp  = cnt + 2;
        float* accum  = (float*)(numComp + 2);
        float* sq     = accum + 2;

        boruvka_init<<<(2 * N + 255) / 256, 256, 0, stream>>>(comp, compBest, (int*)0, cnt, numComp, (int*)0, accum);
        rowsq_kernel<<<dim3(N / 4, 2), 256, 0, stream>>>(x1, x2, sq);
        repr_kernel<<<512, 256, 0, stream>>>((const float4*)x1, (const float4*)x2, accum);
        gemm_dist_kernel<<<dim3(N / BN, N / BM, 1), 256, 0, stream>>>(x1, x2, sq, dist, dist, 0);
        for (int r = 0; r < ROUNDS; ++r) {
            boruvka_scan<<<dim3(N, 1), 256, 0, stream>>>(dist, dist, comp, compBest, numComp, 0);
            boruvka_merge<<<1, 1024, 0, stream>>>(comp, compBest, deaths, cnt, numComp, 0);
        }
        gemm_dist_kernel<<<dim3(N / BN, N / BM, 1), 256, 0, stream>>>(x1, x2, sq, dist, dist, 1);
        for (int r = 0; r < ROUNDS; ++r) {
            boruvka_scan<<<dim3(N, 1), 256, 0, stream>>>(dist, dist, comp, compBest, numComp, 1);
            boruvka_merge<<<1, 1024, 0, stream>>>(comp, compBest, deaths, cnt, numComp, 1);
        }
        sort_kernel<<<2, 1024, 0, stream>>>(deaths, deaths + N);
        final_kernel<<<1, 1024, 0, stream>>>(deaths, deaths + N, accum, out);
    }
}

// Round 5
// 489.763 us; speedup vs baseline: 1.8095x; 1.8095x over previous
//
#include <hip/hip_runtime.h>

#define N 4096
#define D 512
#define BIG 1e30f
#define ROUNDS 12
#define CMAX 2048
#define NW (N / 32)

typedef unsigned long long u64;
typedef unsigned short u16;
typedef __bf16 bf16x8 __attribute__((ext_vector_type(8)));
typedef float floatx4 __attribute__((ext_vector_type(4)));

// ---------------- row squared norms
__global__ __launch_bounds__(256) void rowsq_kernel(const float* __restrict__ x1,
                                                    const float* __restrict__ x2,
                                                    float* __restrict__ sq) {
    int m = blockIdx.y;
    const float* x = m ? x2 : x1;
    int wave = threadIdx.x >> 6, lane = threadIdx.x & 63;
    int row = blockIdx.x * 4 + wave;
    const float4* xr = (const float4*)(x + (size_t)row * D);
    float4 a = xr[lane * 2], b = xr[lane * 2 + 1];
    float s = 0.f;
    s = fmaf(a.x, a.x, s); s = fmaf(a.y, a.y, s); s = fmaf(a.z, a.z, s); s = fmaf(a.w, a.w, s);
    s = fmaf(b.x, b.x, s); s = fmaf(b.y, b.y, s); s = fmaf(b.z, b.z, s); s = fmaf(b.w, b.w, s);
#pragma unroll
    for (int off = 32; off > 0; off >>= 1) s += __shfl_down(s, off, 64);
    if (lane == 0) sq[(size_t)m * N + row] = s;
}

// ---------------- dist via bf16-split MFMA GEMM (unchanged from R3)
#define BM 128
#define BN 128
#define BK 32

__global__ __launch_bounds__(256) void gemm_dist_kernel(const float* __restrict__ x1,
                                                        const float* __restrict__ x2,
                                                        const float* __restrict__ sqn,
                                                        float* __restrict__ dist1,
                                                        float* __restrict__ dist2,
                                                        int m0) {
    const int m = m0 + blockIdx.z;
    const float* x = m ? x2 : x1;
    const float* SQ = sqn + (size_t)m * N;
    float* dist = m ? dist2 : dist1;

    __shared__ u16 Ah[BM * BK];
    __shared__ u16 Al[BM * BK];
    __shared__ u16 Bh[BN * BK];
    __shared__ u16 Bl[BN * BK];

    const int tid = threadIdx.x;
    const int wave = tid >> 6, lane = tid & 63;
    const int wm = wave >> 1, wn = wave & 1;
    const int row0 = blockIdx.y * BM, col0 = blockIdx.x * BN;

    floatx4 acc[4][4] = {};

    const int sr = tid >> 1;
    const int sh = tid & 1;

    for (int k0 = 0; k0 < D; k0 += BK) {
        __syncthreads();
        {
            const float4* ga = (const float4*)(x + (size_t)(row0 + sr) * D + k0 + sh * 16);
            const float4* gb = (const float4*)(x + (size_t)(col0 + sr) * D + k0 + sh * 16);
            float4 av[4], bv[4];
#pragma unroll
            for (int q = 0; q < 4; ++q) { av[q] = ga[q]; bv[q] = gb[q]; }
            int hA[8], lA[8], hB[8], lB[8];
#pragma unroll
            for (int q = 0; q < 4; ++q) {
                const float* af = &av[q].x;
                const float* bf = &bv[q].x;
#pragma unroll
                for (int e = 0; e < 2; ++e) {
                    unsigned u0 = __float_as_uint(af[2 * e]);
                    unsigned u1 = __float_as_uint(af[2 * e + 1]);
                    hA[q * 2 + e] = (int)((u0 >> 16) | (u1 & 0xffff0000u));
                    float l0 = af[2 * e] - __uint_as_float(u0 & 0xffff0000u);
                    float l1 = af[2 * e + 1] - __uint_as_float(u1 & 0xffff0000u);
                    lA[q * 2 + e] = (int)((__float_as_uint(l0) >> 16) | (__float_as_uint(l1) & 0xffff0000u));
                    unsigned w0 = __float_as_uint(bf[2 * e]);
                    unsigned w1 = __float_as_uint(bf[2 * e + 1]);
                    hB[q * 2 + e] = (int)((w0 >> 16) | (w1 & 0xffff0000u));
                    float m0_ = bf[2 * e] - __uint_as_float(w0 & 0xffff0000u);
                    float m1_ = bf[2 * e + 1] - __uint_as_float(w1 & 0xffff0000u);
                    lB[q * 2 + e] = (int)((__float_as_uint(m0_) >> 16) | (__float_as_uint(m1_) & 0xffff0000u));
                }
            }
            int* dAh = (int*)(Ah + sr * BK + sh * 16);
            int* dAl = (int*)(Al + sr * BK + sh * 16);
            int* dBh = (int*)(Bh + sr * BK + sh * 16);
            int* dBl = (int*)(Bl + sr * BK + sh * 16);
            *(int4*)(dAh) = make_int4(hA[0], hA[1], hA[2], hA[3]);
            *(int4*)(dAh + 4) = make_int4(hA[4], hA[5], hA[6], hA[7]);
            *(int4*)(dAl) = make_int4(lA[0], lA[1], lA[2], lA[3]);
            *(int4*)(dAl + 4) = make_int4(lA[4], lA[5], lA[6], lA[7]);
            *(int4*)(dBh) = make_int4(hB[0], hB[1], hB[2], hB[3]);
            *(int4*)(dBh + 4) = make_int4(hB[4], hB[5], hB[6], hB[7]);
            *(int4*)(dBl) = make_int4(lB[0], lB[1], lB[2], lB[3]);
            *(int4*)(dBl + 4) = make_int4(lB[4], lB[5], lB[6], lB[7]);
        }
        __syncthreads();

        const int fo = (lane >> 4) * 8;
        const int fm = lane & 15;
        bf16x8 ah[4], al[4], bh[4], bl[4];
#pragma unroll
        for (int s = 0; s < 4; ++s) {
            ah[s] = *(bf16x8*)(Ah + (wm * 64 + s * 16 + fm) * BK + fo);
            al[s] = *(bf16x8*)(Al + (wm * 64 + s * 16 + fm) * BK + fo);
            bh[s] = *(bf16x8*)(Bh + (wn * 64 + s * 16 + fm) * BK + fo);
            bl[s] = *(bf16x8*)(Bl + (wn * 64 + s * 16 + fm) * BK + fo);
        }
#pragma unroll
        for (int i = 0; i < 4; ++i)
#pragma unroll
            for (int j = 0; j < 4; ++j) {
                acc[i][j] = __builtin_amdgcn_mfma_f32_16x16x32_bf16(ah[i], bh[j], acc[i][j], 0, 0, 0);
                acc[i][j] = __builtin_amdgcn_mfma_f32_16x16x32_bf16(al[i], bh[j], acc[i][j], 0, 0, 0);
                acc[i][j] = __builtin_amdgcn_mfma_f32_16x16x32_bf16(ah[i], bl[j], acc[i][j], 0, 0, 0);
            }
    }

    const int lr = lane & 15;
    const int lq = lane >> 4;
    float sc[4];
#pragma unroll
    for (int ns = 0; ns < 4; ++ns) sc[ns] = SQ[col0 + wn * 64 + ns * 16 + lr];
#pragma unroll
    for (int ms = 0; ms < 4; ++ms) {
        const int rb = row0 + wm * 64 + ms * 16 + lq * 4;
        float srow[4];
#pragma unroll
        for (int r = 0; r < 4; ++r) srow[r] = SQ[rb + r];
#pragma unroll
        for (int ns = 0; ns < 4; ++ns) {
            const int col = col0 + wn * 64 + ns * 16 + lr;
#pragma unroll
            for (int r = 0; r < 4; ++r) {
                const int row = rb + r;
                float d2 = srow[r] + sc[ns] - 2.0f * acc[ms][ns][r];
                float dv = (row == col) ? BIG : sqrtf(fmaxf(d2, 1e-12f));
                dist[(size_t)row * N + col] = dv;
            }
        }
    }
}

// ---------------- Boruvka common init
__global__ void boruvka_init(int* __restrict__ comp, u64* __restrict__ compBest,
                             int* __restrict__ comp_c,
                             int* __restrict__ cnt, int* __restrict__ numComp,
                             int* __restrict__ numC1, float* __restrict__ accum) {
    int idx = blockIdx.x * blockDim.x + threadIdx.x;
    if (idx < 2 * N) {
        comp[idx] = idx & (N - 1);
        compBest[idx] = ~0ull;
    }
    if (comp_c && idx < 2 * CMAX) comp_c[idx] = idx & (CMAX - 1);
    if (idx == 0) {
        cnt[0] = 0; cnt[1] = 0;
        numComp[0] = N; numComp[1] = N;
        if (numC1) { numC1[0] = 0; numC1[1] = 0; }
        accum[0] = 0.f;
    }
}

// ---------------- full-matrix scan (round 1, and Tier B/C all rounds)
__global__ __launch_bounds__(256) void boruvka_scan(const float* __restrict__ dist1,
                                                    const float* __restrict__ dist2,
                                                    const int* __restrict__ comp,
                                                    u64* __restrict__ compBest,
                                                    const int* __restrict__ numComp,
                                                    int m0) {
    const int m = m0 + blockIdx.y;
    if (numComp[m] <= 1) return;
    const float* dist = (m == 0) ? dist1 : dist2;
    const int* cp = comp + (size_t)m * N;
    u64* cb = compBest + (size_t)m * N;
    const int r = blockIdx.x;
    const int myc = cp[r];
    const float4* row4 = (const float4*)(dist + (size_t)r * N);
    const int4* cp4 = (const int4*)cp;
    const int t = threadIdx.x;
    u64 best = ~0ull;
#pragma unroll
    for (int k = 0; k < 4; ++k) {
        int c4 = t + 256 * k;
        float4 v = row4[c4];
        int4 cj = cp4[c4];
        int j0 = c4 * 4;
        u64 p0 = (cj.x != myc) ? ((((u64)__float_as_uint(v.x)) << 32) | (unsigned)(j0 + 0)) : ~0ull;
        u64 p1 = (cj.y != myc) ? ((((u64)__float_as_uint(v.y)) << 32) | (unsigned)(j0 + 1)) : ~0ull;
        u64 p2 = (cj.z != myc) ? ((((u64)__float_as_uint(v.z)) << 32) | (unsigned)(j0 + 2)) : ~0ull;
        u64 p3 = (cj.w != myc) ? ((((u64)__float_as_uint(v.w)) << 32) | (unsigned)(j0 + 3)) : ~0ull;
        u64 q0 = p0 < p1 ? p0 : p1;
        u64 q1 = p2 < p3 ? p2 : p3;
        u64 q = q0 < q1 ? q0 : q1;
        best = q < best ? q : best;
    }
#pragma unroll
    for (int off = 32; off > 0; off >>= 1) {
        u64 o = __shfl_down(best, off, 64);
        best = o < best ? o : best;
    }
    if ((t & 63) == 0) atomicMin(cb + myc, best);
}

// ---------------- Tier B/C merge (R3, unchanged)
__global__ __launch_bounds__(1024) void boruvka_merge(int* __restrict__ comp,
                                                      u64* __restrict__ compBest,
                                                      float* __restrict__ deaths,
                                                      int* __restrict__ cnt,
                                                      int* __restrict__ numComp,
                                                      int m0) {
    const int m = m0 + blockIdx.x;
    if (numComp[m] <= 1) return;
    int* cp = comp + (size_t)m * N;
    u64* cb = compBest + (size_t)m * N;
    float* dth = deaths + (size_t)m * N;
    const int t = threadIdx.x;
    __shared__ int pa[N];
    __shared__ int pb[N];
    __shared__ int done;
    __shared__ unsigned flagbits[NW];

    for (int c = t; c < N; c += 1024) {
        u64 best = cb[c];
        int p = c;
        if (best != ~0ull) {
            int j = (int)(unsigned)best;
            int c2 = cp[j];
            u64 best2 = cb[c2];
            int j2 = (int)(unsigned)best2;
            bool mutual = (cp[j2] == c);
            if (!(mutual && c < c2)) {
                p = c2;
                int idx = atomicAdd(cnt + m, 1);
                dth[idx] = __uint_as_float((unsigned)(best >> 32));
            }
        }
        pa[c] = p;
    }

    int* A = pa;
    int* B = pb;
    while (true) {
        __syncthreads();
        if (t == 0) done = 1;
        __syncthreads();
        bool ch = false;
        for (int c = t; c < N; c += 1024) {
            int g = A[A[c]];
            B[c] = g;
            ch |= (g != A[c]);
        }
        if (ch) done = 0;
        __syncthreads();
        int* tmp = A; A = B; B = tmp;
        if (done) break;
    }

    for (int w = t; w < NW; w += 1024) flagbits[w] = 0u;
    __syncthreads();
    for (int i = t; i < N; i += 1024) {
        int root = A[cp[i]];
        cp[i] = root;
        atomicOr(&flagbits[root >> 5], 1u << (root & 31));
    }
    for (int c = t; c < N; c += 1024) cb[c] = ~0ull;
    __syncthreads();
    if (t < 64) {
        int s = 0;
        for (int w = t; w < NW; w += 64) s += __popc(flagbits[w]);
#pragma unroll
        for (int off = 32; off > 0; off >>= 1) s += __shfl_down(s, off, 64);
        if (t == 0) numComp[m] = s;
    }
}

// ---------------- Tier A: merge round 1 + dense relabel + member lists
__global__ __launch_bounds__(1024) void merge1_kernel(int* __restrict__ comp,
                                                      u64* __restrict__ compBest,
                                                      float* __restrict__ deaths,
                                                      int* __restrict__ cnt,
                                                      int* __restrict__ numComp,
                                                      int* __restrict__ numC1,
                                                      int* __restrict__ memberList,
                                                      int* __restrict__ compStart) {
    const int m = blockIdx.x;
    int* cp = comp + (size_t)m * N;
    u64* cb = compBest + (size_t)m * N;
    float* dth = deaths + (size_t)m * N;
    int* mlist = memberList + (size_t)m * N;
    int* cstart = compStart + (size_t)m * (CMAX + 1);
    const int t = threadIdx.x;

    __shared__ int pa[N];
    __shared__ int pb[N];
    __shared__ unsigned flagbits[NW];
    __shared__ int wpc[NW];
    __shared__ int cnts[CMAX];
    __shared__ int cnts2[CMAX];
    __shared__ int done;

    for (int c = t; c < N; c += 1024) {
        u64 best = cb[c];
        int p = c;
        if (best != ~0ull) {
            int j = (int)(unsigned)best;
            int c2 = cp[j];
            u64 best2 = cb[c2];
            int j2 = (int)(unsigned)best2;
            bool mutual = (cp[j2] == c);
            if (!(mutual && c < c2)) {
                p = c2;
                int idx = atomicAdd(cnt + m, 1);
                dth[idx] = __uint_as_float((unsigned)(best >> 32));
            }
        }
        pa[c] = p;
    }

    int* A = pa;
    int* B = pb;
    while (true) {
        __syncthreads();
        if (t == 0) done = 1;
        __syncthreads();
        bool ch = false;
        for (int c = t; c < N; c += 1024) {
            int g = A[A[c]];
            B[c] = g;
            ch |= (g != A[c]);
        }
        if (ch) done = 0;
        __syncthreads();
        int* tmp = A; A = B; B = tmp;
        if (done) break;
    }

    for (int w = t; w < NW; w += 1024) flagbits[w] = 0u;
    __syncthreads();
    for (int i = t; i < N; i += 1024)
        atomicOr(&flagbits[A[i] >> 5], 1u << (A[i] & 31));
    __syncthreads();
    if (t < NW) wpc[t] = __popc(flagbits[t]);
    __syncthreads();
    for (int off = 1; off < NW; off <<= 1) {
        int v = 0;
        if (t < NW) v = wpc[t] + ((t >= off) ? wpc[t - off] : 0);
        __syncthreads();
        if (t < NW) wpc[t] = v;
        __syncthreads();
    }
    for (int i = t; i < N; i += 1024) {
        int root = A[i];
        int w = root >> 5, b = root & 31;
        int base = w ? wpc[w - 1] : 0;
        unsigned mask = b ? ((1u << b) - 1u) : 0u;
        cp[i] = base + __popc(flagbits[w] & mask);
    }
    for (int c = t; c < CMAX; c += 1024) cnts[c] = 0;
    __syncthreads();
    for (int i = t; i < N; i += 1024) atomicAdd(&cnts[cp[i]], 1);
    __syncthreads();
    int* S = cnts; int* T_ = cnts2;
    for (int off = 1; off < CMAX; off <<= 1) {
        for (int c = t; c < CMAX; c += 1024)
            T_[c] = S[c] + ((c >= off) ? S[c - off] : 0);
        __syncthreads();
        int* tmp = S; S = T_; T_ = tmp;
    }
    for (int c = t; c <= CMAX; c += 1024) cstart[c] = (c == 0) ? 0 : S[c - 1];
    for (int c = t; c < CMAX; c += 1024) T_[c] = (c == 0) ? 0 : S[c - 1];
    __syncthreads();
    for (int i = t; i < N; i += 1024) {
        int pos = atomicAdd(&T_[cp[i]], 1);
        mlist[pos] = i;
    }
    for (int c = t; c < N; c += 1024) cb[c] = ~0ull;
    if (t == 0) {
        int C1 = wpc[NW - 1];
        numC1[m] = C1;
        numComp[m] = C1;
    }
}

// ---------------- Tier A phase A: per-row component mins, written in-place over dist[i][0..CMAX-1]
// one block per row -> perfectly balanced
__global__ __launch_bounds__(256) void rowmin_kernel(float* __restrict__ dist1,
                                                     float* __restrict__ dist2,
                                                     const int* __restrict__ comp) {
    const int m = blockIdx.y;
    float* dist = m ? dist2 : dist1;
    const int* cp = comp + (size_t)m * N;
    const int i = blockIdx.x;
    float* row = dist + (size_t)i * N;
    const float4* row4 = (const float4*)row;
    const int4* cp4 = (const int4*)cp;
    __shared__ unsigned bins[CMAX];
    const int t = threadIdx.x;
    for (int b = t; b < CMAX; b += 256) bins[b] = 0x7f800000u; // +inf
    __syncthreads();
#pragma unroll
    for (int k = 0; k < 4; ++k) {
        int q = t + 256 * k;
        float4 v = row4[q];
        int4 cj = cp4[q];
        atomicMin(&bins[cj.x], __float_as_uint(v.x));
        atomicMin(&bins[cj.y], __float_as_uint(v.y));
        atomicMin(&bins[cj.z], __float_as_uint(v.z));
        atomicMin(&bins[cj.w], __float_as_uint(v.w));
    }
    __syncthreads();
    for (int b = t; b < CMAX; b += 256) row[b] = __uint_as_float(bins[b]);
}

// ---------------- Tier A phase B: column-wise min over member rows -> distc[c][b]
// grid (c, colchunk, m); block work = |members| x 1KB coalesced loads
__global__ __launch_bounds__(256) void colmin_kernel(const float* __restrict__ dist1,
                                                     const float* __restrict__ dist2,
                                                     const int* __restrict__ memberList,
                                                     const int* __restrict__ compStart,
                                                     const int* __restrict__ numC1,
                                                     float* __restrict__ distc) {
    const int m = blockIdx.z;
    const int c = blockIdx.x;
    const int C1 = numC1[m];
    if (c >= C1) return;
    const float* dist = m ? dist2 : dist1;
    const int* mlist = memberList + (size_t)m * N;
    const int* cstart = compStart + (size_t)m * (CMAX + 1);
    const int b = blockIdx.y * 256 + threadIdx.x;
    const int s0 = cstart[c], s1 = cstart[c + 1];
    float mn = BIG;
    for (int k = s0; k < s1; ++k) {
        const int i = mlist[k];
        float v = dist[(size_t)i * N + b];
        mn = fminf(mn, v);
    }
    distc[((size_t)m * CMAX + c) * CMAX + b] = (b == c) ? BIG : mn;
}

// ---------------- Tier A: scan on contracted matrix
__global__ __launch_bounds__(256) void scan_c_kernel(const float* __restrict__ distc,
                                                     const int* __restrict__ comp_c,
                                                     u64* __restrict__ compBest,
                                                     const int* __restrict__ numComp,
                                                     const int* __restrict__ numC1) {
    const int m = blockIdx.y;
    if (numComp[m] <= 1) return;
    const int C1 = numC1[m];
    const int r = blockIdx.x;
    if (r >= C1) return;
    const int* cc = comp_c + (size_t)m * CMAX;
    u64* cb = compBest + (size_t)m * N;
    const int myc = cc[r];
    const float4* row4 = (const float4*)(distc + ((size_t)m * CMAX + r) * CMAX);
    const int4* cc4 = (const int4*)cc;
    const int t = threadIdx.x;
    u64 best = ~0ull;
#pragma unroll
    for (int k = 0; k < 2; ++k) {
        int q = t + 256 * k;
        float4 v = row4[q];
        int4 cj = cc4[q];
        int j0 = q * 4;
        u64 p0 = (j0 + 0 < C1 && cj.x != myc) ? ((((u64)__float_as_uint(v.x)) << 32) | (unsigned)(j0 + 0)) : ~0ull;
        u64 p1 = (j0 + 1 < C1 && cj.y != myc) ? ((((u64)__float_as_uint(v.y)) << 32) | (unsigned)(j0 + 1)) : ~0ull;
        u64 p2 = (j0 + 2 < C1 && cj.z != myc) ? ((((u64)__float_as_uint(v.z)) << 32) | (unsigned)(j0 + 2)) : ~0ull;
        u64 p3 = (j0 + 3 < C1 && cj.w != myc) ? ((((u64)__float_as_uint(v.w)) << 32) | (unsigned)(j0 + 3)) : ~0ull;
        u64 q0 = p0 < p1 ? p0 : p1;
        u64 q1 = p2 < p3 ? p2 : p3;
        u64 qq = q0 < q1 ? q0 : q1;
        best = qq < best ? qq : best;
    }
#pragma unroll
    for (int off = 32; off > 0; off >>= 1) {
        u64 o = __shfl_down(best, off, 64);
        best = o < best ? o : best;
    }
    if ((t & 63) == 0) atomicMin(cb + myc, best);
}

// ---------------- Tier A: merge on contracted graph
__global__ __launch_bounds__(1024) void merge_c_kernel(int* __restrict__ comp_c,
                                                       u64* __restrict__ compBest,
                                                       float* __restrict__ deaths,
                                                       int* __restrict__ cnt,
                                                       int* __restrict__ numComp,
                                                       const int* __restrict__ numC1) {
    const int m = blockIdx.x;
    if (numComp[m] <= 1) return;
    const int C1 = numC1[m];
    int* cc = comp_c + (size_t)m * CMAX;
    u64* cb = compBest + (size_t)m * N;
    float* dth = deaths + (size_t)m * N;
    const int t = threadIdx.x;
    __shared__ int pa[CMAX];
    __shared__ int pb[CMAX];
    __shared__ unsigned flagbits[CMAX / 32];
    __shared__ int done;

    for (int c = t; c < C1; c += 1024) {
        u64 best = cb[c];
        int p = c;
        if (best != ~0ull) {
            int j = (int)(unsigned)best;
            int c2 = cc[j];
            u64 best2 = cb[c2];
            int j2 = (int)(unsigned)best2;
            bool mutual = (cc[j2] == c);
            if (!(mutual && c < c2)) {
                p = c2;
                int idx = atomicAdd(cnt + m, 1);
                dth[idx] = __uint_as_float((unsigned)(best >> 32));
            }
        }
        pa[c] = p;
    }

    int* A = pa;
    int* B = pb;
    while (true) {
        __syncthreads();
        if (t == 0) done = 1;
        __syncthreads();
        bool ch = false;
        for (int c = t; c < C1; c += 1024) {
            int g = A[A[c]];
            B[c] = g;
            ch |= (g != A[c]);
        }
        if (ch) done = 0;
        __syncthreads();
        int* tmp = A; A = B; B = tmp;
        if (done) break;
    }

    for (int w = t; w < CMAX / 32; w += 1024) flagbits[w] = 0u;
    __syncthreads();
    for (int j = t; j < C1; j += 1024) {
        int root = A[cc[j]];
        cc[j] = root;
        atomicOr(&flagbits[root >> 5], 1u << (root & 31));
    }
    for (int c = t; c < C1; c += 1024) cb[c] = ~0ull;
    __syncthreads();
    if (t < 64) {
        int s = 0;
        for (int w = t; w < CMAX / 32; w += 64) s += __popc(flagbits[w]);
#pragma unroll
        for (int off = 32; off > 0; off >>= 1) s += __shfl_down(s, off, 64);
        if (t == 0) numComp[m] = s;
    }
}

// ---------------- bitonic sort of 4096 (4095 deaths + one BIG pad) in LDS
__global__ __launch_bounds__(1024) void sort_kernel(float* __restrict__ deaths1,
                                                    float* __restrict__ deaths2) {
    float* deaths = (blockIdx.x == 0) ? deaths1 : deaths2;
    __shared__ float s[N];
    const int tid = threadIdx.x;
    for (int i = tid; i < N; i += 1024)
        s[i] = (i < N - 1) ? deaths[i] : BIG;
    __syncthreads();
    for (int k = 2; k <= N; k <<= 1) {
        for (int jj = k >> 1; jj > 0; jj >>= 1) {
            for (int t = tid; t < N; t += 1024) {
                int ixj = t ^ jj;
                if (ixj > t) {
                    float a = s[t], b = s[ixj];
                    bool up = ((t & k) == 0);
                    bool sw = up ? (a > b) : (a < b);
                    if (sw) { s[t] = b; s[ixj] = a; }
                }
            }
            __syncthreads();
        }
    }
    for (int i = tid; i < N; i += 1024) deaths[i] = s[i];
}

// ---------------- representation loss
__global__ void repr_kernel(const float4* __restrict__ a, const float4* __restrict__ b,
                            float* __restrict__ accum) {
    int idx = blockIdx.x * blockDim.x + threadIdx.x;
    int stride = gridDim.x * blockDim.x;
    float s = 0.f;
    for (int i = idx; i < (N * D / 4); i += stride) {
        float4 va = a[i], vb = b[i];
        float dx = va.x - vb.x, dy = va.y - vb.y, dz = va.z - vb.z, dw = va.w - vb.w;
        s = fmaf(dx, dx, s); s = fmaf(dy, dy, s); s = fmaf(dz, dz, s); s = fmaf(dw, dw, s);
    }
#pragma unroll
    for (int off = 32; off > 0; off >>= 1) s += __shfl_down(s, off, 64);
    if ((threadIdx.x & 63) == 0) atomicAdd(accum, s);
}

// ---------------- final
__global__ __launch_bounds__(1024) void final_kernel(const float* __restrict__ s1,
                                                     const float* __restrict__ s2,
                                                     const float* __restrict__ accum,
                                                     float* __restrict__ out) {
    __shared__ float wsum[16];
    float sum = 0.f;
    for (int i = threadIdx.x; i < N - 1; i += 1024) {
        float a = s1[i], b = s2[i];
        sum += fminf(fabsf(a - b), 0.5f * (a + b));
    }
#pragma unroll
    for (int off = 32; off > 0; off >>= 1) sum += __shfl_down(sum, off, 64);
    int lane = threadIdx.x & 63, wid = threadIdx.x >> 6;
    if (lane == 0) wsum[wid] = sum;
    __syncthreads();
    if (threadIdx.x == 0) {
        float tot = 0.f;
        for (int k = 0; k < 16; ++k) tot += wsum[k];
        out[0] = accum[0] * (1.0f / ((float)N * (float)D)) + tot;
    }
}

extern "C" void kernel_launch(void* const* d_in, const int* in_sizes, int n_in,
                              void* d_out, int out_size, void* d_ws, size_t ws_size,
                              hipStream_t stream) {
    const float* x1 = (const float*)d_in[0];
    const float* x2 = (const float*)d_in[1];
    float* out = (float*)d_out;
    float* ws = (float*)d_ws;

    const size_t nn = (size_t)N * N;
    const size_t cc2 = (size_t)CMAX * CMAX;

    // Tier A layout
    float* dist1 = ws;
    float* dist2 = ws + nn;
    float* distc = ws + 2 * nn;
    u64* compBestA = (u64*)(distc + 2 * cc2);
    int* compA     = (int*)(compBestA + 2 * N);
    int* comp_c    = compA + 2 * N;
    int* memberList = comp_c + 2 * CMAX;
    int* compStart  = memberList + 2 * N;
    float* deathsA  = (float*)(compStart + 2 * (CMAX + 1));
    int* cntA       = (int*)(deathsA + 2 * N);
    int* numCompA   = cntA + 2;
    int* numC1      = numCompA + 2;
    float* accumA   = (float*)(numC1 + 2);
    float* sqA      = accumA + 2;
    const size_t need_A = (size_t)((char*)(sqA + 2 * N) - (char*)ws);

    // Tier B layout (R3)
    const size_t state_floats = 2 * N * 2 + 2 * N + 2 * N + 8 + 2 * N;
    const size_t need_B = (2 * nn + state_floats) * sizeof(float);

    if (ws_size >= need_A) {
        boruvka_init<<<(2 * N + 255) / 256, 256, 0, stream>>>(compA, compBestA, comp_c, cntA, numCompA, numC1, accumA);
        rowsq_kernel<<<dim3(N / 4, 2), 256, 0, stream>>>(x1, x2, sqA);
        repr_kernel<<<512, 256, 0, stream>>>((const float4*)x1, (const float4*)x2, accumA);
        gemm_dist_kernel<<<dim3(N / BN, N / BM, 2), 256, 0, stream>>>(x1, x2, sqA, dist1, dist2, 0);
        // round 1 on full matrix
        boruvka_scan<<<dim3(N, 2), 256, 0, stream>>>(dist1, dist2, compA, compBestA, numCompA, 0);
        merge1_kernel<<<2, 1024, 0, stream>>>(compA, compBestA, deathsA, cntA, numCompA, numC1, memberList, compStart);
        // balanced contraction: per-row component mins (in-place), then column-wise min per component
        rowmin_kernel<<<dim3(N, 2), 256, 0, stream>>>(dist1, dist2, compA);
        colmin_kernel<<<dim3(CMAX, CMAX / 256, 2), 256, 0, stream>>>(dist1, dist2, memberList, compStart, numC1, distc);
        // remaining rounds on contracted matrix
        for (int r = 1; r < ROUNDS; ++r) {
            scan_c_kernel<<<dim3(CMAX, 2), 256, 0, stream>>>(distc, comp_c, compBestA, numCompA, numC1);
            merge_c_kernel<<<2, 1024, 0, stream>>>(comp_c, compBestA, deathsA, cntA, numCompA, numC1);
        }
        sort_kernel<<<2, 1024, 0, stream>>>(deathsA, deathsA + N);
        final_kernel<<<1, 1024, 0, stream>>>(deathsA, deathsA + N, accumA, out);
    } else if (ws_size >= need_B) {
        u64* compBest = (u64*)(ws + 2 * nn);
        int* comp     = (int*)(compBest + 2 * N);
        float* deaths = (float*)(comp + 2 * N);
        int* cnt      = (int*)(deaths + 2 * N);
        int* numComp  = cnt + 2;
        float* accum  = (float*)(numComp + 2);
        float* sq     = accum + 2;

        boruvka_init<<<(2 * N + 255) / 256, 256, 0, stream>>>(comp, compBest, (int*)0, cnt, numComp, (int*)0, accum);
        rowsq_kernel<<<dim3(N / 4, 2), 256, 0, stream>>>(x1, x2, sq);
        repr_kernel<<<512, 256, 0, stream>>>((const float4*)x1, (const float4*)x2, accum);
        gemm_dist_kernel<<<dim3(N / BN, N / BM, 2), 256, 0, stream>>>(x1, x2, sq, dist1, dist2, 0);
        for (int r = 0; r < ROUNDS; ++r) {
            boruvka_scan<<<dim3(N, 2), 256, 0, stream>>>(dist1, dist2, comp, compBest, numComp, 0);
            boruvka_merge<<<2, 1024, 0, stream>>>(comp, compBest, deaths, cnt, numComp, 0);
        }
        sort_kernel<<<2, 1024, 0, stream>>>(deaths, deaths + N);
        final_kernel<<<1, 1024, 0, stream>>>(deaths, deaths + N, accum, out);
    } else {
        // sequential fallback
        float* dist = ws;
        u64* compBest = (u64*)(ws + nn);
        int* comp     = (int*)(compBest + 2 * N);
        float* deaths = (float*)(comp + 2 * N);
        int* cnt      = (int*)(deaths + 2 * N);
        int* numComp  = cnt + 2;
        float* accum  = (float*)(numComp + 2);
        float* sq     = accum + 2;

        boruvka_init<<<(2 * N + 255) / 256, 256, 0, stream>>>(comp, compBest, (int*)0, cnt, numComp, (int*)0, accum);
        rowsq_kernel<<<dim3(N / 4, 2), 256, 0, stream>>>(x1, x2, sq);
        repr_kernel<<<512, 256, 0, stream>>>((const float4*)x1, (const float4*)x2, accum);
        gemm_dist_kernel<<<dim3(N / BN, N / BM, 1), 256, 0, stream>>>(x1, x2, sq, dist, dist, 0);
        for (int r = 0; r < ROUNDS; ++r) {
            boruvka_scan<<<dim3(N, 1), 256, 0, stream>>>(dist, dist, comp, compBest, numComp, 0);
            boruvka_merge<<<1, 1024, 0, stream>>>(comp, compBest, deaths, cnt, numComp, 0);
        }
        gemm_dist_kernel<<<dim3(N / BN, N / BM, 1), 256, 0, stream>>>(x1, x2, sq, dist, dist, 1);
        for (int r = 0; r < ROUNDS; ++r) {
            boruvka_scan<<<dim3(N, 1), 256, 0, stream>>>(dist, dist, comp, compBest, numComp, 1);
            boruvka_merge<<<1, 1024, 0, stream>>>(comp, compBest, deaths, cnt, numComp, 1);
        }
        sort_kernel<<<2, 1024, 0, stream>>>(deaths, deaths + N);
        final_kernel<<<1, 1024, 0, stream>>>(deaths, deaths + N, accum, out);
    }
}